// Round 1
// baseline (500.489 us; speedup 1.0000x reference)
//
#include <hip/hip_runtime.h>
#include <cmath>

typedef unsigned int uint32;
typedef __bf16 bf16;
typedef __bf16 bf16x8 __attribute__((ext_vector_type(8)));
typedef float f32x4 __attribute__((ext_vector_type(4)));

#define LVLS 10
#define TSIZE 65536
#define TMASK 65535u
#define PRIME2 2654435761u
#define PRIME3 805459861u

// ws layout (bf16 elements):
//   [0,     4096): W1t[64][64]  (W1t[n][k] = W1[k][n], k>=40 zero)
//   [4096,  8192): W2t[64][64]
//   [8192,  9216): W3t[16][64]  (n>=13 zero)
//   [9216, 9216+TAB_ELEMS): tables bf16 [10][65536][4]   (only if ws big enough)
#define WOFF_W1 0
#define WOFF_W2 4096
#define WOFF_W3 8192
#define W_ELEMS 9216
#define TAB_OFF 9216
#define TAB_ELEMS (LVLS * TSIZE * 4)

struct KParams { float resf[LVLS]; };

// ---------------- weight / table prep ----------------
__global__ void prep_kernel(const float* __restrict__ W1, const float* __restrict__ W2,
                            const float* __restrict__ W3, const float* __restrict__ tables,
                            bf16* __restrict__ ws, int do_tab) {
  int tid = blockIdx.x * 256 + threadIdx.x;
  if (tid < W_ELEMS) {
    float v;
    if (tid < 4096) {
      int n = tid >> 6, k = tid & 63;
      v = (k < 40) ? W1[k * 64 + n] : 0.f;
    } else if (tid < 8192) {
      int t2 = tid - 4096; int n = t2 >> 6, k = t2 & 63;
      v = W2[k * 64 + n];
    } else {
      int t3 = tid - 8192; int n = t3 >> 6, k = t3 & 63;
      v = (n < 13) ? W3[k * 13 + n] : 0.f;
    }
    ws[tid] = (bf16)v;
  }
  if (do_tab) {
    int stride = gridDim.x * 256 * 4;
    for (int i4 = tid * 4; i4 < TAB_ELEMS; i4 += stride) {
      float4 v = *(const float4*)(tables + i4);
      bf16* dst = ws + TAB_OFF + i4;
      dst[0] = (bf16)v.x; dst[1] = (bf16)v.y; dst[2] = (bf16)v.z; dst[3] = (bf16)v.w;
    }
  }
}

// ---------------- device helpers ----------------
__device__ __forceinline__ float selu_f(float v) {
  float neg = 1.6732632423543772f * expm1f(v);
  return 1.0507009873554805f * (v > 0.f ? v : neg);
}

// One 64x64 @ 64x64 GEMM stage for this wave: A rows from LDS (wave-private 64
// rows), B^T from global (ws image), bias from global, SELU, write bf16 back
// into the same wave-private LDS rows (C-layout -> A-layout for next stage).
__device__ __forceinline__ void gemm_stage(const bf16* __restrict__ Arow,
                                           const bf16* __restrict__ Bbase,
                                           const float* __restrict__ bvec,
                                           bf16* __restrict__ Hwr, int lr) {
  float bias[4];
#pragma unroll
  for (int nt = 0; nt < 4; ++nt) bias[nt] = bvec[nt * 16 + lr];
  f32x4 acc[4][4];
#pragma unroll
  for (int ms = 0; ms < 4; ++ms)
#pragma unroll
    for (int nt = 0; nt < 4; ++nt) {
      f32x4 a = {bias[nt], bias[nt], bias[nt], bias[nt]};
      acc[ms][nt] = a;
    }
  bf16x8 Bf[2][4];
#pragma unroll
  for (int ks = 0; ks < 2; ++ks)
#pragma unroll
    for (int nt = 0; nt < 4; ++nt)
      Bf[ks][nt] = *(const bf16x8*)(Bbase + nt * 1024 + ks * 32);
#pragma unroll
  for (int ks = 0; ks < 2; ++ks) {
    bf16x8 Af[4];
#pragma unroll
    for (int ms = 0; ms < 4; ++ms) Af[ms] = *(const bf16x8*)(Arow + ms * 1152 + ks * 32);
#pragma unroll
    for (int ms = 0; ms < 4; ++ms)
#pragma unroll
      for (int nt = 0; nt < 4; ++nt)
        acc[ms][nt] = __builtin_amdgcn_mfma_f32_16x16x32_bf16(Af[ms], Bf[ks][nt], acc[ms][nt], 0, 0, 0);
  }
  // epilogue: SELU -> bf16 -> LDS (rows are wave-private; same-wave DS ops are
  // in-order, and a __syncthreads() in the caller adds belt-and-suspenders)
#pragma unroll
  for (int ms = 0; ms < 4; ++ms)
#pragma unroll
    for (int nt = 0; nt < 4; ++nt)
#pragma unroll
      for (int r = 0; r < 4; ++r)
        Hwr[(ms * 16 + r) * 72 + nt * 16 + lr] = (bf16)selu_f(acc[ms][nt][r]);
}

// ---------------- fused encode + MLP ----------------
// 256 threads (4 waves) per block, 256 points per block.
// LDS: Hbuf[256][72] bf16 (stride 72 => 144B rows: 16B aligned for b128,
// bank shift 4/row => 2-way aliasing (free)).
template <bool TB>
__global__ __launch_bounds__(256, 3)
void ngp_fused(const float* __restrict__ x, const float* __restrict__ cr,
               const float* __restrict__ tables, const bf16* __restrict__ ws,
               const float* __restrict__ b1, const float* __restrict__ b2,
               const float* __restrict__ b3, float* __restrict__ out,
               int N, KParams kp) {
  __shared__ bf16 Hbuf[256 * 72];
  const int tid = threadIdx.x;
  const int n = blockIdx.x * 256 + tid;
  const bool valid = n < N;
  const int ncl = valid ? n : 0;

  const float px = x[ncl * 3 + 0];
  const float py = x[ncl * 3 + 1];
  const float pz = x[ncl * 3 + 2];
  const float crv = cr[ncl];

  float feat[40];
#pragma unroll
  for (int l = 0; l < LVLS; ++l) {
    const float rs = kp.resf[l];
    float xs = px * rs, ys = py * rs, zs = pz * rs;
    float bx = floorf(xs), by = floorf(ys), bz = floorf(zs);
    float fx = xs - bx, fy = ys - by, fz = zs - bz;
    uint32 cx = (uint32)bx, cy = (uint32)by, cz = (uint32)bz;
    uint32 hx0 = cx, hx1 = cx + 1u;
    uint32 hy0 = cy * PRIME2, hy1 = hy0 + PRIME2;
    uint32 hz0 = cz * PRIME3, hz1 = hz0 + PRIME3;
    uint32 idx[8];
    idx[0] = (hx0 ^ hy0 ^ hz0) & TMASK; idx[1] = (hx0 ^ hy0 ^ hz1) & TMASK;
    idx[2] = (hx0 ^ hy1 ^ hz0) & TMASK; idx[3] = (hx0 ^ hy1 ^ hz1) & TMASK;
    idx[4] = (hx1 ^ hy0 ^ hz0) & TMASK; idx[5] = (hx1 ^ hy0 ^ hz1) & TMASK;
    idx[6] = (hx1 ^ hy1 ^ hz0) & TMASK; idx[7] = (hx1 ^ hy1 ^ hz1) & TMASK;

    float f[8][4];
    if (TB) {
      const uint2* tb = ((const uint2*)(ws + TAB_OFF)) + l * TSIZE;
#pragma unroll
      for (int c = 0; c < 8; ++c) {
        uint2 q = tb[idx[c]];
        f[c][0] = __uint_as_float(q.x << 16);
        f[c][1] = __uint_as_float(q.x & 0xffff0000u);
        f[c][2] = __uint_as_float(q.y << 16);
        f[c][3] = __uint_as_float(q.y & 0xffff0000u);
      }
    } else {
      const float4* tb = ((const float4*)tables) + l * TSIZE;
#pragma unroll
      for (int c = 0; c < 8; ++c) {
        float4 q = tb[idx[c]];
        f[c][0] = q.x; f[c][1] = q.y; f[c][2] = q.z; f[c][3] = q.w;
      }
    }
    float wx1 = fx, wx0 = 1.f - fx, wy1 = fy, wy0 = 1.f - fy, wz1 = fz, wz0 = 1.f - fz;
    float wxy00 = wx0 * wy0, wxy01 = wx0 * wy1, wxy10 = wx1 * wy0, wxy11 = wx1 * wy1;
    float w[8] = {wxy00 * wz0, wxy00 * wz1, wxy01 * wz0, wxy01 * wz1,
                  wxy10 * wz0, wxy10 * wz1, wxy11 * wz0, wxy11 * wz1};
    float a0 = 0.f, a1 = 0.f, a2 = 0.f, a3 = 0.f;
#pragma unroll
    for (int c = 0; c < 8; ++c) {
      a0 = fmaf(w[c], f[c][0], a0);
      a1 = fmaf(w[c], f[c][1], a1);
      a2 = fmaf(w[c], f[c][2], a2);
      a3 = fmaf(w[c], f[c][3], a3);
    }
    // scaling = erf(1/sqrt(max(PLS*4*l*(cr*0.5), 1e-12))) = erf(rsqrt(max(4*l*cr,1e-12)))
    float s = erff(rsqrtf(fmaxf(4.0f * (float)l * crv, 1e-12f)));
    feat[0 * 10 + l] = a0 * s;
    feat[1 * 10 + l] = a1 * s;
    feat[2 * 10 + l] = a2 * s;
    feat[3 * 10 + l] = a3 * s;
  }

  // features -> LDS row (cols 0..39 data, 40..63 zeros for K-padding)
  {
    bf16* row = Hbuf + tid * 72;
#pragma unroll
    for (int c = 0; c < 5; ++c) {
      bf16x8 v;
#pragma unroll
      for (int j = 0; j < 8; ++j) v[j] = (bf16)feat[c * 8 + j];
      *(bf16x8*)(row + c * 8) = v;
    }
    bf16x8 z;
#pragma unroll
    for (int j = 0; j < 8; ++j) z[j] = (bf16)0.f;
    *(bf16x8*)(row + 40) = z;
    *(bf16x8*)(row + 48) = z;
    *(bf16x8*)(row + 56) = z;
  }
  __syncthreads();

  // ---- per-wave MLP on its own 64 rows ----
  const int w = tid >> 6;
  const int lane = tid & 63;
  const int lr = lane & 15;
  const int quad = lane >> 4;

  const bf16* Arow = Hbuf + (w * 64 + lr) * 72 + quad * 8;
  bf16* Hwr = Hbuf + (w * 64 + quad * 4) * 72;

  gemm_stage(Arow, ws + WOFF_W1 + lr * 64 + quad * 8, b1, Hwr, lr);
  __syncthreads();
  gemm_stage(Arow, ws + WOFF_W2 + lr * 64 + quad * 8, b2, Hwr, lr);
  __syncthreads();

  // GEMM3: [64x64] @ [64x13] (padded to 16 cols), no activation, store f32
  {
    float b3v = (lr < 13) ? b3[lr] : 0.f;
    f32x4 acc3[4];
#pragma unroll
    for (int ms = 0; ms < 4; ++ms) {
      f32x4 a = {b3v, b3v, b3v, b3v};
      acc3[ms] = a;
    }
    const bf16* B3b = ws + WOFF_W3 + lr * 64 + quad * 8;
    bf16x8 B3[2];
    B3[0] = *(const bf16x8*)(B3b);
    B3[1] = *(const bf16x8*)(B3b + 32);
#pragma unroll
    for (int ks = 0; ks < 2; ++ks) {
      bf16x8 Af[4];
#pragma unroll
      for (int ms = 0; ms < 4; ++ms) Af[ms] = *(const bf16x8*)(Arow + ms * 1152 + ks * 32);
#pragma unroll
      for (int ms = 0; ms < 4; ++ms)
        acc3[ms] = __builtin_amdgcn_mfma_f32_16x16x32_bf16(Af[ms], B3[ks], acc3[ms], 0, 0, 0);
    }
    const int rbase = blockIdx.x * 256 + w * 64 + quad * 4;
#pragma unroll
    for (int ms = 0; ms < 4; ++ms)
#pragma unroll
      for (int r = 0; r < 4; ++r) {
        int rowg = rbase + ms * 16 + r;
        if (lr < 13 && rowg < N) out[rowg * 13 + lr] = acc3[ms][r];
      }
  }
}

// ---------------- host ----------------
extern "C" void kernel_launch(void* const* d_in, const int* in_sizes, int n_in,
                              void* d_out, int out_size, void* d_ws, size_t ws_size,
                              hipStream_t stream) {
  const float* x      = (const float*)d_in[0];
  const float* cr     = (const float*)d_in[1];
  const float* tables = (const float*)d_in[2];
  const float* W1     = (const float*)d_in[3];
  const float* b1     = (const float*)d_in[4];
  const float* W2     = (const float*)d_in[5];
  const float* b2     = (const float*)d_in[6];
  const float* W3     = (const float*)d_in[7];
  const float* b3     = (const float*)d_in[8];
  float* out = (float*)d_out;
  const int N = in_sizes[1];

  // RES computed with the exact double arithmetic the Python reference uses
  // (same glibc exp/log/pow/floor) so hash indices match bit-for-bit.
  KParams kp;
  double B = exp((log(16.0 * pow(2.0, 10.0)) - log(16.0)) / 9.0);
  for (int l = 0; l < LVLS; ++l) kp.resf[l] = (float)floor(16.0 * pow(B, (double)l));

  bf16* ws = (bf16*)d_ws;
  const bool tb = ws_size >= (size_t)(W_ELEMS + TAB_ELEMS) * sizeof(bf16);

  int prep_blocks = tb ? ((TAB_ELEMS / 4 + 255) / 256) : ((W_ELEMS + 255) / 256);
  prep_kernel<<<prep_blocks, 256, 0, stream>>>(W1, W2, W3, tables, ws, (int)tb);

  int blocks = (N + 255) / 256;
  if (tb)
    ngp_fused<true><<<blocks, 256, 0, stream>>>(x, cr, tables, ws, b1, b2, b3, out, N, kp);
  else
    ngp_fused<false><<<blocks, 256, 0, stream>>>(x, cr, tables, ws, b1, b2, b3, out, N, kp);
}

// Round 2
// 482.852 us; speedup vs baseline: 1.0365x; 1.0365x over previous
//
#include <hip/hip_runtime.h>
#include <cmath>

typedef unsigned int uint32;
typedef __bf16 bf16;
typedef __bf16 bf16x8 __attribute__((ext_vector_type(8)));
typedef float f32x4 __attribute__((ext_vector_type(4)));

#define LVLS 10
#define TSIZE 65536
#define TMASK 65535u
#define PRIME2 2654435761u
#define PRIME3 805459861u

// ---- ws layout (bytes) ----
//   [0,      18432): W1t/W2t/W3t bf16 images (9216 elems)
//   [18432,  18472): dq[10] f32  (scale/127 per level)
//   [18496,  18536): scales[10] u32 (absmax bits, atomicMax target; memset 0)
//   [18560,  18560+2621440): int8 table [10][65536][4]  (64B-aligned)
#define WOFF_W1 0
#define WOFF_W2 4096
#define WOFF_W3 8192
#define W_ELEMS 9216
#define DQ_OFF 18432
#define SC_OFF 18496
#define TAB_OFF_B 18560
#define TAB_ELEMS_F (LVLS * TSIZE * 4)   // f32 source elems
#define WS_NEEDED ((size_t)TAB_OFF_B + (size_t)TAB_ELEMS_F)

struct KParams { float resf[LVLS]; };

// ---------------- prep 1: per-level absmax ----------------
__global__ void scale_kernel(const float* __restrict__ tables, unsigned* __restrict__ scales) {
  int tid = blockIdx.x * 256 + threadIdx.x;
  int i4 = tid * 4;
  if (i4 >= TAB_ELEMS_F) return;
  float4 v = *(const float4*)(tables + i4);
  float m = fmaxf(fmaxf(fabsf(v.x), fabsf(v.y)), fmaxf(fabsf(v.z), fabsf(v.w)));
#pragma unroll
  for (int off = 32; off; off >>= 1) m = fmaxf(m, __shfl_xor(m, off, 64));
  if ((threadIdx.x & 63) == 0) {
    int l = i4 >> 18;  // 65536*4 = 2^18 elems per level; waves never straddle
    atomicMax(scales + l, __float_as_uint(m));
  }
}

// ---------------- prep 2: weight transpose + int8 quantize ----------------
__global__ void quant_kernel(const float* __restrict__ W1, const float* __restrict__ W2,
                             const float* __restrict__ W3, const float* __restrict__ tables,
                             char* __restrict__ ws8, int do_tab) {
  int tid = blockIdx.x * 256 + threadIdx.x;
  bf16* wsb = (bf16*)ws8;
  if (tid < W_ELEMS) {
    float v;
    if (tid < 4096) {
      int n = tid >> 6, k = tid & 63;
      v = (k < 40) ? W1[k * 64 + n] : 0.f;
    } else if (tid < 8192) {
      int t2 = tid - 4096; int n = t2 >> 6, k = t2 & 63;
      v = W2[k * 64 + n];
    } else {
      int t3 = tid - 8192; int n = t3 >> 6, k = t3 & 63;
      v = (n < 13) ? W3[k * 13 + n] : 0.f;
    }
    wsb[tid] = (bf16)v;
  }
  const unsigned* scales = (const unsigned*)(ws8 + SC_OFF);
  if (tid < LVLS) {
    float s = __uint_as_float(scales[tid]);
    ((float*)(ws8 + DQ_OFF))[tid] = s * (1.0f / 127.0f);
  }
  if (do_tab) {
    int i4 = tid * 4;
    if (i4 < TAB_ELEMS_F) {
      float4 v = *(const float4*)(tables + i4);
      int l = i4 >> 18;
      float s = __uint_as_float(scales[l]);
      float r = (s > 0.f) ? 127.f / s : 0.f;
      int q0 = (int)rintf(fminf(fmaxf(v.x * r, -127.f), 127.f));
      int q1 = (int)rintf(fminf(fmaxf(v.y * r, -127.f), 127.f));
      int q2 = (int)rintf(fminf(fmaxf(v.z * r, -127.f), 127.f));
      int q3 = (int)rintf(fminf(fmaxf(v.w * r, -127.f), 127.f));
      unsigned p = (q0 & 0xff) | ((q1 & 0xff) << 8) | ((q2 & 0xff) << 16) | ((q3 & 0xff) << 24);
      *(unsigned*)(ws8 + TAB_OFF_B + i4) = p;
    }
  }
}

// ---------------- device helpers ----------------
__device__ __forceinline__ float selu_f(float v) {
  // neg branch: 1.6733*(e^v - 1). __expf -> v_exp_f32; cancellation error ~1e-7
  // absolute on ~1e-4-scale activations, well inside the error budget.
  float neg = 1.6732632423543772f * (__expf(v) - 1.0f);
  return 1.0507009873554805f * (v > 0.f ? v : neg);
}

__device__ __forceinline__ void gemm_stage(const bf16* __restrict__ Arow,
                                           const bf16* __restrict__ Bbase,
                                           const float* __restrict__ bvec,
                                           bf16* __restrict__ Hwr, int lr) {
  float bias[4];
#pragma unroll
  for (int nt = 0; nt < 4; ++nt) bias[nt] = bvec[nt * 16 + lr];
  f32x4 acc[4][4];
#pragma unroll
  for (int ms = 0; ms < 4; ++ms)
#pragma unroll
    for (int nt = 0; nt < 4; ++nt) {
      f32x4 a = {bias[nt], bias[nt], bias[nt], bias[nt]};
      acc[ms][nt] = a;
    }
  bf16x8 Bf[2][4];
#pragma unroll
  for (int ks = 0; ks < 2; ++ks)
#pragma unroll
    for (int nt = 0; nt < 4; ++nt)
      Bf[ks][nt] = *(const bf16x8*)(Bbase + nt * 1024 + ks * 32);
#pragma unroll
  for (int ks = 0; ks < 2; ++ks) {
    bf16x8 Af[4];
#pragma unroll
    for (int ms = 0; ms < 4; ++ms) Af[ms] = *(const bf16x8*)(Arow + ms * 1152 + ks * 32);
#pragma unroll
    for (int ms = 0; ms < 4; ++ms)
#pragma unroll
      for (int nt = 0; nt < 4; ++nt)
        acc[ms][nt] = __builtin_amdgcn_mfma_f32_16x16x32_bf16(Af[ms], Bf[ks][nt], acc[ms][nt], 0, 0, 0);
  }
#pragma unroll
  for (int ms = 0; ms < 4; ++ms)
#pragma unroll
    for (int nt = 0; nt < 4; ++nt)
#pragma unroll
      for (int r = 0; r < 4; ++r)
        Hwr[(ms * 16 + r) * 72 + nt * 16 + lr] = (bf16)selu_f(acc[ms][nt][r]);
}

// ---------------- fused encode + MLP ----------------
// 256 threads (4 waves), 256 points per block. LDS Hbuf stride 72 (144B rows:
// 16B-aligned for b128; 2-way bank aliasing = free). 4 blocks/CU by LDS.
template <bool TB>
__global__ __launch_bounds__(256, 4)
void ngp_fused(const float* __restrict__ x, const float* __restrict__ cr,
               const float* __restrict__ tables, const char* __restrict__ ws8,
               const float* __restrict__ b1, const float* __restrict__ b2,
               const float* __restrict__ b3, float* __restrict__ out,
               int N, KParams kp) {
  __shared__ bf16 Hbuf[256 * 72];
  const int tid = threadIdx.x;
  const int n = blockIdx.x * 256 + tid;
  const int ncl = (n < N) ? n : 0;

  const float px = x[ncl * 3 + 0];
  const float py = x[ncl * 3 + 1];
  const float pz = x[ncl * 3 + 2];
  const float crv = cr[ncl];
  const float* dq = (const float*)(ws8 + DQ_OFF);

  float feat[40];
#pragma unroll
  for (int l = 0; l < LVLS; ++l) {
    const float rs = kp.resf[l];
    float xs = px * rs, ys = py * rs, zs = pz * rs;
    float bx = floorf(xs), by = floorf(ys), bz = floorf(zs);
    float fx = xs - bx, fy = ys - by, fz = zs - bz;
    uint32 cx = (uint32)bx, cy = (uint32)by, cz = (uint32)bz;
    uint32 hx0 = cx, hx1 = cx + 1u;
    uint32 hy0 = cy * PRIME2, hy1 = hy0 + PRIME2;
    uint32 hz0 = cz * PRIME3, hz1 = hz0 + PRIME3;
    uint32 idx[8];
    idx[0] = (hx0 ^ hy0 ^ hz0) & TMASK; idx[1] = (hx0 ^ hy0 ^ hz1) & TMASK;
    idx[2] = (hx0 ^ hy1 ^ hz0) & TMASK; idx[3] = (hx0 ^ hy1 ^ hz1) & TMASK;
    idx[4] = (hx1 ^ hy0 ^ hz0) & TMASK; idx[5] = (hx1 ^ hy0 ^ hz1) & TMASK;
    idx[6] = (hx1 ^ hy1 ^ hz0) & TMASK; idx[7] = (hx1 ^ hy1 ^ hz1) & TMASK;

    float f[8][4];
    if (TB) {
      const unsigned* tb = ((const unsigned*)(ws8 + TAB_OFF_B)) + l * TSIZE;
#pragma unroll
      for (int c = 0; c < 8; ++c) {
        unsigned q = tb[idx[c]];
        f[c][0] = (float)(signed char)(q & 0xff);
        f[c][1] = (float)(signed char)((q >> 8) & 0xff);
        f[c][2] = (float)(signed char)((q >> 16) & 0xff);
        f[c][3] = (float)(signed char)(q >> 24);
      }
    } else {
      const float4* tb = ((const float4*)tables) + l * TSIZE;
#pragma unroll
      for (int c = 0; c < 8; ++c) {
        float4 q = tb[idx[c]];
        f[c][0] = q.x; f[c][1] = q.y; f[c][2] = q.z; f[c][3] = q.w;
      }
    }
    float wx1 = fx, wx0 = 1.f - fx, wy1 = fy, wy0 = 1.f - fy, wz1 = fz, wz0 = 1.f - fz;
    float wxy00 = wx0 * wy0, wxy01 = wx0 * wy1, wxy10 = wx1 * wy0, wxy11 = wx1 * wy1;
    float w[8] = {wxy00 * wz0, wxy00 * wz1, wxy01 * wz0, wxy01 * wz1,
                  wxy10 * wz0, wxy10 * wz1, wxy11 * wz0, wxy11 * wz1};
    float a0 = 0.f, a1 = 0.f, a2 = 0.f, a3 = 0.f;
#pragma unroll
    for (int c = 0; c < 8; ++c) {
      a0 = fmaf(w[c], f[c][0], a0);
      a1 = fmaf(w[c], f[c][1], a1);
      a2 = fmaf(w[c], f[c][2], a2);
      a3 = fmaf(w[c], f[c][3], a3);
    }
    // scaling = erf(rsqrt(max(4*l*cr, 1e-12))); int8 dequant folded in
    float s = erff(rsqrtf(fmaxf(4.0f * (float)l * crv, 1e-12f)));
    if (TB) s *= dq[l];
    feat[0 * 10 + l] = a0 * s;
    feat[1 * 10 + l] = a1 * s;
    feat[2 * 10 + l] = a2 * s;
    feat[3 * 10 + l] = a3 * s;
  }

  {
    bf16* row = Hbuf + tid * 72;
#pragma unroll
    for (int c = 0; c < 5; ++c) {
      bf16x8 v;
#pragma unroll
      for (int j = 0; j < 8; ++j) v[j] = (bf16)feat[c * 8 + j];
      *(bf16x8*)(row + c * 8) = v;
    }
    bf16x8 z;
#pragma unroll
    for (int j = 0; j < 8; ++j) z[j] = (bf16)0.f;
    *(bf16x8*)(row + 40) = z;
    *(bf16x8*)(row + 48) = z;
    *(bf16x8*)(row + 56) = z;
  }
  __syncthreads();

  const int w = tid >> 6;
  const int lane = tid & 63;
  const int lr = lane & 15;
  const int quad = lane >> 4;
  const bf16* wsb = (const bf16*)ws8;

  const bf16* Arow = Hbuf + (w * 64 + lr) * 72 + quad * 8;
  bf16* Hwr = Hbuf + (w * 64 + quad * 4) * 72;

  gemm_stage(Arow, wsb + WOFF_W1 + lr * 64 + quad * 8, b1, Hwr, lr);
  __syncthreads();
  gemm_stage(Arow, wsb + WOFF_W2 + lr * 64 + quad * 8, b2, Hwr, lr);
  __syncthreads();

  {
    float b3v = (lr < 13) ? b3[lr] : 0.f;
    f32x4 acc3[4];
#pragma unroll
    for (int ms = 0; ms < 4; ++ms) {
      f32x4 a = {b3v, b3v, b3v, b3v};
      acc3[ms] = a;
    }
    const bf16* B3b = wsb + WOFF_W3 + lr * 64 + quad * 8;
    bf16x8 B3[2];
    B3[0] = *(const bf16x8*)(B3b);
    B3[1] = *(const bf16x8*)(B3b + 32);
#pragma unroll
    for (int ks = 0; ks < 2; ++ks) {
      bf16x8 Af[4];
#pragma unroll
      for (int ms = 0; ms < 4; ++ms) Af[ms] = *(const bf16x8*)(Arow + ms * 1152 + ks * 32);
#pragma unroll
      for (int ms = 0; ms < 4; ++ms)
        acc3[ms] = __builtin_amdgcn_mfma_f32_16x16x32_bf16(Af[ms], B3[ks], acc3[ms], 0, 0, 0);
    }
    const int rbase = blockIdx.x * 256 + w * 64 + quad * 4;
#pragma unroll
    for (int ms = 0; ms < 4; ++ms)
#pragma unroll
      for (int r = 0; r < 4; ++r) {
        int rowg = rbase + ms * 16 + r;
        if (lr < 13 && rowg < N) out[rowg * 13 + lr] = acc3[ms][r];
      }
  }
}

// ---------------- host ----------------
extern "C" void kernel_launch(void* const* d_in, const int* in_sizes, int n_in,
                              void* d_out, int out_size, void* d_ws, size_t ws_size,
                              hipStream_t stream) {
  const float* x      = (const float*)d_in[0];
  const float* cr     = (const float*)d_in[1];
  const float* tables = (const float*)d_in[2];
  const float* W1     = (const float*)d_in[3];
  const float* b1     = (const float*)d_in[4];
  const float* W2     = (const float*)d_in[5];
  const float* b2     = (const float*)d_in[6];
  const float* W3     = (const float*)d_in[7];
  const float* b3     = (const float*)d_in[8];
  float* out = (float*)d_out;
  const int N = in_sizes[1];

  // RES with the exact double arithmetic Python uses (bit-identical hashing).
  KParams kp;
  double B = exp((log(16.0 * pow(2.0, 10.0)) - log(16.0)) / 9.0);
  for (int l = 0; l < LVLS; ++l) kp.resf[l] = (float)floor(16.0 * pow(B, (double)l));

  char* ws8 = (char*)d_ws;
  const bool tb = ws_size >= WS_NEEDED;

  const int qblocks = (TAB_ELEMS_F / 4 + 255) / 256;  // 2560: covers table + weights
  if (tb) {
    hipMemsetAsync(ws8 + SC_OFF, 0, 64, stream);
    scale_kernel<<<qblocks, 256, 0, stream>>>(tables, (unsigned*)(ws8 + SC_OFF));
    quant_kernel<<<qblocks, 256, 0, stream>>>(W1, W2, W3, tables, ws8, 1);
  } else {
    quant_kernel<<<(W_ELEMS + 255) / 256, 256, 0, stream>>>(W1, W2, W3, tables, ws8, 0);
  }

  int blocks = (N + 255) / 256;
  if (tb)
    ngp_fused<true><<<blocks, 256, 0, stream>>>(x, cr, tables, ws8, b1, b2, b3, out, N, kp);
  else
    ngp_fused<false><<<blocks, 256, 0, stream>>>(x, cr, tables, ws8, b1, b2, b3, out, N, kp);
}